// Round 9
// baseline (347.284 us; speedup 1.0000x reference)
//
#include <hip/hip_runtime.h>

#define N_NODES 50000
#define N_EDGES 800000
#define N_GRAPHS 64
#define SCAN_B 256
#define SCAN_NBLK ((N_NODES + SCAN_B - 1) / SCAN_B)   // 196

typedef __attribute__((ext_vector_type(8))) short short8;
typedef __attribute__((ext_vector_type(4))) float floatx4;

// fp32 -> bf16 round-to-nearest-even
__device__ __forceinline__ unsigned short f2bf(float f) {
    unsigned int u = __float_as_uint(f);
    u += 0x7FFFu + ((u >> 16) & 1u);
    return (unsigned short)(u >> 16);
}
__device__ __forceinline__ float bf2f(unsigned short h) {
    return __uint_as_float(((unsigned int)h) << 16);
}

// ========== prep: zero counts + pooled, cast W2/W3 to packed bf16 B-frag layout ====

__global__ void k_prep(int* counts, float* pooled,
                       const float* __restrict__ W2, const float* __restrict__ W3,
                       unsigned short* Wb2, unsigned short* Wb3) {
    int i = blockIdx.x * blockDim.x + threadIdx.x;
    if (i < N_NODES) counts[i] = 0;
    int j = i - N_NODES;
    if (j >= 0 && j < N_GRAPHS * 128) pooled[j] = 0.0f;
    int k = i - N_NODES - N_GRAPHS * 128;
    if (k >= 0 && k < 64 * 128) {
        int kk = k >> 7, n = k & 127;
        Wb2[(((kk >> 3) * 128) + n) * 8 + (kk & 7)] = f2bf(W2[k]);
    }
    int l = i - N_NODES - N_GRAPHS * 128 - 64 * 128;
    if (l >= 0 && l < 128 * 128) {
        int kk = l >> 7, n = l & 127;
        Wb3[(((kk >> 3) * 128) + n) * 8 + (kk & 7)] = f2bf(W3[l]);
    }
}

// ================= CSR build (real edges only; self-loop analytic) ====

__global__ void k_hist(const int* __restrict__ dst, int* counts) {
    int i = blockIdx.x * blockDim.x + threadIdx.x;
    if (i < N_EDGES) atomicAdd(&counts[dst[i]], 1);
}

__global__ void k_scan1(const int* __restrict__ counts, int* row_ptr, int* blksum) {
    __shared__ int s[SCAN_B];
    int i = blockIdx.x * SCAN_B + threadIdx.x;
    int c = (i < N_NODES) ? counts[i] : 0;
    s[threadIdx.x] = c;
    __syncthreads();
    for (int off = 1; off < SCAN_B; off <<= 1) {
        int v = (threadIdx.x >= off) ? s[threadIdx.x - off] : 0;
        __syncthreads();
        s[threadIdx.x] += v;
        __syncthreads();
    }
    if (i < N_NODES) row_ptr[i] = s[threadIdx.x] - c;   // exclusive
    if (threadIdx.x == SCAN_B - 1) blksum[blockIdx.x] = s[SCAN_B - 1];
}

__global__ void k_scan2(int* blksum) {
    __shared__ int s[SCAN_B];
    int t = threadIdx.x;
    int c = (t < SCAN_NBLK) ? blksum[t] : 0;
    s[t] = c;
    __syncthreads();
    for (int off = 1; off < SCAN_B; off <<= 1) {
        int v = (t >= off) ? s[t - off] : 0;
        __syncthreads();
        s[t] += v;
        __syncthreads();
    }
    if (t < SCAN_NBLK) blksum[t] = s[t] - c;            // exclusive
}

__global__ void k_scan3(int* row_ptr, const int* __restrict__ blksum,
                        int* cursor, const int* __restrict__ counts, float* dinv,
                        const float* __restrict__ x, float* __restrict__ xs) {
    int i = blockIdx.x * blockDim.x + threadIdx.x;
    if (i < N_NODES) {
        int v = row_ptr[i] + blksum[i / SCAN_B];
        row_ptr[i] = v;
        cursor[i] = v;
        float di = rsqrtf((float)(counts[i] + 1));
        dinv[i] = di;
        xs[i * 3 + 0] = x[i * 3 + 0] * di;
        xs[i * 3 + 1] = x[i * 3 + 1] * di;
        xs[i * 3 + 2] = x[i * 3 + 2] * di;
    }
    if (i == 0) row_ptr[N_NODES] = N_EDGES;
}

__global__ void k_fill(const int* __restrict__ src, const int* __restrict__ dst,
                       int* cursor, int* csr_src) {
    int e = blockIdx.x * blockDim.x + threadIdx.x;
    if (e >= N_EDGES) return;
    int pos = atomicAdd(&cursor[dst[e]], 1);
    csr_src[pos] = src[e];
}

// ================= layer 1: agg width 3 + small GEMM ==================

__global__ void k_agg3(const float* __restrict__ xs, const int* __restrict__ row_ptr,
                       const int* __restrict__ csr_src, const float* __restrict__ dinv,
                       float* __restrict__ out) {
    int n = blockIdx.x * blockDim.x + threadIdx.x;
    if (n >= N_NODES) return;
    int lo = row_ptr[n], hi = row_ptr[n + 1];
    float a0 = xs[n * 3 + 0], a1 = xs[n * 3 + 1], a2 = xs[n * 3 + 2];
    for (int i = lo; i < hi; ++i) {
        int s = csr_src[i];
        a0 += xs[s * 3 + 0];
        a1 += xs[s * 3 + 1];
        a2 += xs[s * 3 + 2];
    }
    float din = dinv[n];
    out[n * 3 + 0] = a0 * din;
    out[n * 3 + 1] = a1 * din;
    out[n * 3 + 2] = a2 * din;
}

template<int IN_W, int OUT_W, int NPB>
__global__ void k_node_gemm(const float* __restrict__ h, const float* __restrict__ W,
                            const float* __restrict__ b, const float* __restrict__ dinv,
                            unsigned short* __restrict__ hb) {
    __shared__ float rows[NPB][IN_W];
    int n0 = blockIdx.x * NPB;
    int j = threadIdx.x;                         // blockDim.x == OUT_W
    for (int t = j; t < NPB * IN_W; t += OUT_W) {
        int m = t / IN_W, k = t - m * IN_W;
        int n = n0 + m;
        rows[m][k] = (n < N_NODES) ? h[(size_t)n * IN_W + k] : 0.0f;
    }
    __syncthreads();
    float acc[NPB];
    float bj = b[j];
#pragma unroll
    for (int m = 0; m < NPB; ++m) acc[m] = bj;
#pragma unroll
    for (int k = 0; k < IN_W; ++k) {
        float wk = W[k * OUT_W + j];
#pragma unroll
        for (int m = 0; m < NPB; ++m) acc[m] += rows[m][k] * wk;
    }
#pragma unroll
    for (int m = 0; m < NPB; ++m) {
        int n = n0 + m;
        if (n < N_NODES)
            hb[(size_t)n * OUT_W + j] = f2bf(fmaxf(acc[m], 0.0f) * dinv[n]);
    }
}

// ====== layer 2 fused: agg64(hb64) -> LDS -> MFMA @ W2 + b2 -> hb128 bf16 ==========
// 1024 thr = 16 waves = 16 nodes (wave-per-node gather, same parallelism as
// standalone agg). sA padded (+8 bf16/row) so A-frag reads are 2-way aliased (free).

__global__ __launch_bounds__(1024) void k_l2_fused(
    const unsigned short* __restrict__ hb64,   // [N][64] bf16, pre-scaled by dinv
    const int* __restrict__ row_ptr, const int* __restrict__ csr_src,
    const float* __restrict__ dinv,
    const unsigned short* __restrict__ Wb,     // packed [8][128][8]
    const float* __restrict__ b,
    unsigned short* __restrict__ out128) {
    __shared__ unsigned short sA[16][72];      // 2.25 KB
    __shared__ float sC[16][128];              // 8 KB
    int tid = threadIdx.x;
    int wave = tid >> 6, lane = tid & 63;
    int n0 = blockIdx.x * 16;
    int n = n0 + wave;                         // N_NODES % 16 == 0 -> always valid
    int lo = row_ptr[n], hi = row_ptr[n + 1];
    float acc = bf2f(hb64[(size_t)n * 64 + lane]);   // self-loop
    for (int base = lo; base < hi; base += 64) {
        int idx = base + lane;
        int sv = csr_src[idx < hi ? idx : hi - 1];
        int cnt = (hi - base < 64) ? (hi - base) : 64;
#pragma unroll 8
        for (int j = 0; j < cnt; ++j) {
            int s = __shfl(sv, j);
            acc += bf2f(hb64[(size_t)s * 64 + lane]);
        }
    }
    sA[wave][lane] = f2bf(acc * dinv[n]);
    __syncthreads();
    if (wave < 8) {                            // wave = col tile t (16 cols each)
        int quad = lane >> 4, l16 = lane & 15;
        floatx4 c4 = (floatx4){0.f, 0.f, 0.f, 0.f};
#pragma unroll
        for (int ks = 0; ks < 2; ++ks) {
            short8 a = *(const short8*)&sA[l16][ks * 32 + quad * 8];
            short8 bf = *(const short8*)(Wb + (((ks * 4 + quad) * 128) + wave * 16 + l16) * 8);
            c4 = __builtin_amdgcn_mfma_f32_16x16x32_bf16(a, bf, c4, 0, 0, 0);
        }
#pragma unroll
        for (int r = 0; r < 4; ++r)
            sC[quad * 4 + r][wave * 16 + l16] = c4[r];
    }
    __syncthreads();
    if (tid < 512) {
        int m = tid >> 5, tj = tid & 31;
        int nn = n0 + m;
        float di = dinv[nn];
        float4 bv = *(const float4*)(b + tj * 4);
        unsigned short h0 = f2bf(fmaxf(sC[m][tj * 4 + 0] + bv.x, 0.f) * di);
        unsigned short h1 = f2bf(fmaxf(sC[m][tj * 4 + 1] + bv.y, 0.f) * di);
        unsigned short h2 = f2bf(fmaxf(sC[m][tj * 4 + 2] + bv.z, 0.f) * di);
        unsigned short h3 = f2bf(fmaxf(sC[m][tj * 4 + 3] + bv.w, 0.f) * di);
        uint2 w2;
        w2.x = (unsigned int)h0 | ((unsigned int)h1 << 16);
        w2.y = (unsigned int)h2 | ((unsigned int)h3 << 16);
        *(uint2*)(out128 + (size_t)nn * 128 + tj * 4) = w2;
    }
}

// ====== layer 3 fused: agg128(hb128) -> LDS -> MFMA @ W3 + b3, relu, mean-pool =====

__global__ __launch_bounds__(1024) void k_l3_fused(
    const unsigned short* __restrict__ hb128,  // [N][128] bf16, pre-scaled by dinv
    const int* __restrict__ row_ptr, const int* __restrict__ csr_src,
    const float* __restrict__ dinv,
    const unsigned short* __restrict__ Wb,     // packed [16][128][8]
    const float* __restrict__ b,
    const int* __restrict__ batch,
    float* __restrict__ pooled) {
    __shared__ unsigned int sAu[16][68];       // 4.25 KB (128 bf16 + 8 pad per row)
    __shared__ float sC[16][128];              // 8 KB
    __shared__ int sb[16];
    int tid = threadIdx.x;
    int wave = tid >> 6, lane = tid & 63;
    int n0 = blockIdx.x * 16;
    int n = n0 + wave;
    int lo = row_ptr[n], hi = row_ptr[n + 1];
    const unsigned int* hbu = (const unsigned int*)hb128;
    unsigned int uo = hbu[(size_t)n * 64 + lane];     // self-loop
    float accx = __uint_as_float(uo << 16);
    float accy = __uint_as_float(uo & 0xffff0000u);
    for (int base = lo; base < hi; base += 64) {
        int idx = base + lane;
        int sv = csr_src[idx < hi ? idx : hi - 1];
        int cnt = (hi - base < 64) ? (hi - base) : 64;
#pragma unroll 8
        for (int j = 0; j < cnt; ++j) {
            int s = __shfl(sv, j);
            unsigned int u = hbu[(size_t)s * 64 + lane];
            accx += __uint_as_float(u << 16);
            accy += __uint_as_float(u & 0xffff0000u);
        }
    }
    float din = dinv[n];
    sAu[wave][lane] = (unsigned int)f2bf(accx * din) | ((unsigned int)f2bf(accy * din) << 16);
    if (lane == 0) sb[wave] = batch[n];
    __syncthreads();
    if (wave < 8) {
        int quad = lane >> 4, l16 = lane & 15;
        floatx4 c4 = (floatx4){0.f, 0.f, 0.f, 0.f};
#pragma unroll
        for (int ks = 0; ks < 4; ++ks) {
            short8 a = *(const short8*)((const unsigned short*)&sAu[l16][0] + ks * 32 + quad * 8);
            short8 bf = *(const short8*)(Wb + (((ks * 4 + quad) * 128) + wave * 16 + l16) * 8);
            c4 = __builtin_amdgcn_mfma_f32_16x16x32_bf16(a, bf, c4, 0, 0, 0);
        }
        float bc = b[wave * 16 + l16];
#pragma unroll
        for (int r = 0; r < 4; ++r)
            sC[quad * 4 + r][wave * 16 + l16] = fmaxf(c4[r] + bc, 0.f);
    }
    __syncthreads();
    if (tid < 128) {
        int g0 = sb[0], g1 = sb[15];
        for (int g = g0; g <= g1; ++g) {
            float s = 0.f;
#pragma unroll
            for (int m = 0; m < 16; ++m)
                if (sb[m] == g) s += sC[m][tid];
            atomicAdd(&pooled[g * 128 + tid], s);
        }
    }
}

// ================= final FC head =================

__device__ __forceinline__ int lower_bound_batch(const int* __restrict__ batch, int val) {
    int lo = 0, hi = N_NODES;
    while (lo < hi) {
        int mid = (lo + hi) >> 1;
        if (batch[mid] < val) lo = mid + 1; else hi = mid;
    }
    return lo;
}

__global__ void k_fc(const float* __restrict__ pooled, const int* __restrict__ batch,
                     const float* __restrict__ Wf1, const float* __restrict__ bf1,
                     const float* __restrict__ Wf2, const float* __restrict__ bf2,
                     float* __restrict__ out) {
    __shared__ float sp[128];
    __shared__ float sh1[64];
    int g = blockIdx.x;
    int t = threadIdx.x;             // 128
    int lo = lower_bound_batch(batch, g);
    int hi = lower_bound_batch(batch, g + 1);
    float inv = 1.0f / fmaxf((float)(hi - lo), 1.0f);
    sp[t] = pooled[g * 128 + t] * inv;
    __syncthreads();
    if (t < 64) {
        float acc = bf1[t];
#pragma unroll 8
        for (int k = 0; k < 128; ++k) acc += sp[k] * Wf1[k * 64 + t];
        sh1[t] = fmaxf(acc, 0.0f);
    }
    __syncthreads();
    if (t < 10) {
        float acc = bf2[t];
#pragma unroll 8
        for (int k = 0; k < 64; ++k) acc += sh1[k] * Wf2[k * 10 + t];
        out[g * 10 + t] = acc;
    }
}

extern "C" void kernel_launch(void* const* d_in, const int* in_sizes, int n_in,
                              void* d_out, int out_size, void* d_ws, size_t ws_size,
                              hipStream_t stream) {
    const float* x     = (const float*)d_in[0];
    const int*   ei    = (const int*)d_in[1];
    const int*   batch = (const int*)d_in[2];
    const float* W1  = (const float*)d_in[3];
    const float* b1  = (const float*)d_in[4];
    const float* W2  = (const float*)d_in[5];
    const float* b2  = (const float*)d_in[6];
    const float* W3  = (const float*)d_in[7];
    const float* b3  = (const float*)d_in[8];
    const float* Wf1 = (const float*)d_in[9];
    const float* bf1 = (const float*)d_in[10];
    const float* Wf2 = (const float*)d_in[11];
    const float* bf2 = (const float*)d_in[12];
    float* out = (float*)d_out;

    const int* src = ei;              // edge_index[0]
    const int* dst = ei + N_EDGES;    // edge_index[1]

    // workspace layout
    float* dinv   = (float*)d_ws;                      // N
    int*   counts = (int*)(dinv + N_NODES);            // N
    int*   row_ptr= counts + N_NODES;                  // N+1
    int*   blksum = row_ptr + N_NODES + 1;             // 256
    int*   cursor = blksum + 256;                      // N
    int*   csr_src= cursor + N_NODES;                  // N_EDGES
    float* xs     = (float*)(csr_src + N_EDGES);       // N*3
    float* a3     = xs + (size_t)N_NODES * 3;          // N*3 (agg3 out)
    unsigned short* Wb2 = (unsigned short*)(a3 + (size_t)N_NODES * 3);  // 8192
    unsigned short* Wb3 = Wb2 + 64 * 128;                               // 16384
    size_t ofs = (size_t)(Wb3 + 128 * 128) - (size_t)d_ws;
    ofs = (ofs + 15) & ~(size_t)15;
    unsigned short* hb64  = (unsigned short*)((char*)d_ws + ofs);       // N*64 bf16
    unsigned short* hb128 = hb64 + (size_t)N_NODES * 64;                // N*128 bf16
    float* pooled = (float*)(hb128 + (size_t)N_NODES * 128);            // G*128

    const int TB = 256;
    const int PREP_N = N_NODES + N_GRAPHS * 128 + 64 * 128 + 128 * 128;

    // ---- prep (zero counts+pooled, cast weights) + CSR build ----
    k_prep<<<(PREP_N + TB - 1) / TB, TB, 0, stream>>>(counts, pooled, W2, W3, Wb2, Wb3);
    k_hist<<<(N_EDGES + TB - 1) / TB, TB, 0, stream>>>(dst, counts);
    k_scan1<<<SCAN_NBLK, SCAN_B, 0, stream>>>(counts, row_ptr, blksum);
    k_scan2<<<1, SCAN_B, 0, stream>>>(blksum);
    k_scan3<<<(N_NODES + TB - 1) / TB, TB, 0, stream>>>(row_ptr, blksum, cursor, counts, dinv, x, xs);
    k_fill<<<(N_EDGES + TB - 1) / TB, TB, 0, stream>>>(src, dst, cursor, csr_src);

    // ---- layer 1: agg3(xs) @ W1 + b1 -> hb64 = bf16(dinv*relu) ----
    k_agg3<<<(N_NODES + TB - 1) / TB, TB, 0, stream>>>(xs, row_ptr, csr_src, dinv, a3);
    k_node_gemm<3, 64, 4><<<(N_NODES + 3) / 4, 64, 0, stream>>>(a3, W1, b1, dinv, hb64);

    // ---- layer 2 fused: agg64 + MFMA -> hb128 ----
    k_l2_fused<<<N_NODES / 16, 1024, 0, stream>>>(hb64, row_ptr, csr_src, dinv, Wb2, b2, hb128);

    // ---- layer 3 fused: agg128 + MFMA + relu + mean-pool ----
    k_l3_fused<<<N_NODES / 16, 1024, 0, stream>>>(hb128, row_ptr, csr_src, dinv, Wb3, b3, batch, pooled);

    // ---- FC head ----
    k_fc<<<N_GRAPHS, 128, 0, stream>>>(pooled, batch, Wf1, bf1, Wf2, bf2, out);
}

// Round 10
// 308.320 us; speedup vs baseline: 1.1264x; 1.1264x over previous
//
#include <hip/hip_runtime.h>

#define N_NODES 50000
#define N_EDGES 800000
#define N_GRAPHS 64
#define SCAN_B 256
#define SCAN_NBLK ((N_NODES + SCAN_B - 1) / SCAN_B)   // 196

typedef __attribute__((ext_vector_type(8))) short short8;
typedef __attribute__((ext_vector_type(4))) float floatx4;

// fp32 -> bf16 round-to-nearest-even
__device__ __forceinline__ unsigned short f2bf(float f) {
    unsigned int u = __float_as_uint(f);
    u += 0x7FFFu + ((u >> 16) & 1u);
    return (unsigned short)(u >> 16);
}
__device__ __forceinline__ float bf2f(unsigned short h) {
    return __uint_as_float(((unsigned int)h) << 16);
}

// ========== prep: zero counts + pooled, cast W2/W3 to packed bf16 B-frag layout ====

__global__ void k_prep(int* counts, float* pooled,
                       const float* __restrict__ W2, const float* __restrict__ W3,
                       unsigned short* Wb2, unsigned short* Wb3) {
    int i = blockIdx.x * blockDim.x + threadIdx.x;
    if (i < N_NODES) counts[i] = 0;
    int j = i - N_NODES;
    if (j >= 0 && j < N_GRAPHS * 128) pooled[j] = 0.0f;
    int k = i - N_NODES - N_GRAPHS * 128;
    if (k >= 0 && k < 64 * 128) {
        int kk = k >> 7, n = k & 127;
        Wb2[(((kk >> 3) * 128) + n) * 8 + (kk & 7)] = f2bf(W2[k]);
    }
    int l = i - N_NODES - N_GRAPHS * 128 - 64 * 128;
    if (l >= 0 && l < 128 * 128) {
        int kk = l >> 7, n = l & 127;
        Wb3[(((kk >> 3) * 128) + n) * 8 + (kk & 7)] = f2bf(W3[l]);
    }
}

// ================= CSR build (real edges only; self-loop analytic) ====

__global__ void k_hist(const int* __restrict__ dst, int* counts) {
    int i = blockIdx.x * blockDim.x + threadIdx.x;
    if (i < N_EDGES) atomicAdd(&counts[dst[i]], 1);
}

__global__ void k_scan1(const int* __restrict__ counts, int* row_ptr, int* blksum) {
    __shared__ int s[SCAN_B];
    int i = blockIdx.x * SCAN_B + threadIdx.x;
    int c = (i < N_NODES) ? counts[i] : 0;
    s[threadIdx.x] = c;
    __syncthreads();
    for (int off = 1; off < SCAN_B; off <<= 1) {
        int v = (threadIdx.x >= off) ? s[threadIdx.x - off] : 0;
        __syncthreads();
        s[threadIdx.x] += v;
        __syncthreads();
    }
    if (i < N_NODES) row_ptr[i] = s[threadIdx.x] - c;   // exclusive
    if (threadIdx.x == SCAN_B - 1) blksum[blockIdx.x] = s[SCAN_B - 1];
}

__global__ void k_scan2(int* blksum) {
    __shared__ int s[SCAN_B];
    int t = threadIdx.x;
    int c = (t < SCAN_NBLK) ? blksum[t] : 0;
    s[t] = c;
    __syncthreads();
    for (int off = 1; off < SCAN_B; off <<= 1) {
        int v = (t >= off) ? s[t - off] : 0;
        __syncthreads();
        s[t] += v;
        __syncthreads();
    }
    if (t < SCAN_NBLK) blksum[t] = s[t] - c;            // exclusive
}

__global__ void k_scan3(int* row_ptr, const int* __restrict__ blksum,
                        int* cursor, const int* __restrict__ counts, float* dinv,
                        const float* __restrict__ x, float* __restrict__ xs) {
    int i = blockIdx.x * blockDim.x + threadIdx.x;
    if (i < N_NODES) {
        int v = row_ptr[i] + blksum[i / SCAN_B];
        row_ptr[i] = v;
        cursor[i] = v;
        float di = rsqrtf((float)(counts[i] + 1));
        dinv[i] = di;
        xs[i * 3 + 0] = x[i * 3 + 0] * di;
        xs[i * 3 + 1] = x[i * 3 + 1] * di;
        xs[i * 3 + 2] = x[i * 3 + 2] * di;
    }
    if (i == 0) row_ptr[N_NODES] = N_EDGES;
}

__global__ void k_fill(const int* __restrict__ src, const int* __restrict__ dst,
                       int* cursor, int* csr_src) {
    int e = blockIdx.x * blockDim.x + threadIdx.x;
    if (e >= N_EDGES) return;
    int pos = atomicAdd(&cursor[dst[e]], 1);
    csr_src[pos] = src[e];
}

// ================= layer 1: agg width 3 + small GEMM ==================

__global__ void k_agg3(const float* __restrict__ xs, const int* __restrict__ row_ptr,
                       const int* __restrict__ csr_src, const float* __restrict__ dinv,
                       float* __restrict__ out) {
    int n = blockIdx.x * blockDim.x + threadIdx.x;
    if (n >= N_NODES) return;
    int lo = row_ptr[n], hi = row_ptr[n + 1];
    float a0 = xs[n * 3 + 0], a1 = xs[n * 3 + 1], a2 = xs[n * 3 + 2];
    for (int i = lo; i < hi; ++i) {
        int s = csr_src[i];
        a0 += xs[s * 3 + 0];
        a1 += xs[s * 3 + 1];
        a2 += xs[s * 3 + 2];
    }
    float din = dinv[n];
    out[n * 3 + 0] = a0 * din;
    out[n * 3 + 1] = a1 * din;
    out[n * 3 + 2] = a2 * din;
}

template<int IN_W, int OUT_W, int NPB>
__global__ void k_node_gemm(const float* __restrict__ h, const float* __restrict__ W,
                            const float* __restrict__ b, const float* __restrict__ dinv,
                            unsigned short* __restrict__ hb) {
    __shared__ float rows[NPB][IN_W];
    int n0 = blockIdx.x * NPB;
    int j = threadIdx.x;                         // blockDim.x == OUT_W
    for (int t = j; t < NPB * IN_W; t += OUT_W) {
        int m = t / IN_W, k = t - m * IN_W;
        int n = n0 + m;
        rows[m][k] = (n < N_NODES) ? h[(size_t)n * IN_W + k] : 0.0f;
    }
    __syncthreads();
    float acc[NPB];
    float bj = b[j];
#pragma unroll
    for (int m = 0; m < NPB; ++m) acc[m] = bj;
#pragma unroll
    for (int k = 0; k < IN_W; ++k) {
        float wk = W[k * OUT_W + j];
#pragma unroll
        for (int m = 0; m < NPB; ++m) acc[m] += rows[m][k] * wk;
    }
#pragma unroll
    for (int m = 0; m < NPB; ++m) {
        int n = n0 + m;
        if (n < N_NODES)
            hb[(size_t)n * OUT_W + j] = f2bf(fmaxf(acc[m], 0.0f) * dinv[n]);
    }
}

// ================= aggregation (barrier-free, wave per node) =====================
// Inner loop: fixed 16-wide fully-unrolled chunk, all 16 gathers issued
// unconditionally (clamped dup addresses -> L1 hits), adds masked by the
// wave-uniform jj<cnt. Guarantees 16 outstanding loads, no serial epilogue.

__global__ void k_agg64(const unsigned short* __restrict__ hb, const int* __restrict__ row_ptr,
                        const int* __restrict__ csr_src, const float* __restrict__ dinv,
                        unsigned short* __restrict__ outb) {
    int wv = (blockIdx.x * blockDim.x + threadIdx.x) >> 6;
    int lane = threadIdx.x & 63;
    if (wv >= N_NODES) return;
    int lo = row_ptr[wv], hi = row_ptr[wv + 1];
    float acc = bf2f(hb[(size_t)wv * 64 + lane]);      // self-loop
    for (int base = lo; base < hi; base += 64) {
        int idx = base + lane;
        int sv = csr_src[idx < hi ? idx : hi - 1];
        int cnt = (hi - base < 64) ? (hi - base) : 64;
        for (int j0 = 0; j0 < cnt; j0 += 16) {
#pragma unroll
            for (int k = 0; k < 16; ++k) {
                int jj = j0 + k;
                int s = __shfl(sv, jj < 64 ? jj : 63);
                float v = bf2f(hb[(size_t)s * 64 + lane]);
                if (jj < cnt) acc += v;                // wave-uniform predicate
            }
        }
    }
    outb[(size_t)wv * 64 + lane] = f2bf(acc * dinv[wv]);
}

__global__ void k_agg128(const unsigned short* __restrict__ hb, const int* __restrict__ row_ptr,
                         const int* __restrict__ csr_src, const float* __restrict__ dinv,
                         unsigned short* __restrict__ outb) {
    int wv = (blockIdx.x * blockDim.x + threadIdx.x) >> 6;
    int lane = threadIdx.x & 63;
    if (wv >= N_NODES) return;
    int lo = row_ptr[wv], hi = row_ptr[wv + 1];
    const unsigned int* hbu = (const unsigned int*)hb;
    unsigned int uo = hbu[(size_t)wv * 64 + lane];     // self-loop
    float accx = __uint_as_float(uo << 16);
    float accy = __uint_as_float(uo & 0xffff0000u);
    for (int base = lo; base < hi; base += 64) {
        int idx = base + lane;
        int sv = csr_src[idx < hi ? idx : hi - 1];
        int cnt = (hi - base < 64) ? (hi - base) : 64;
        for (int j0 = 0; j0 < cnt; j0 += 16) {
#pragma unroll
            for (int k = 0; k < 16; ++k) {
                int jj = j0 + k;
                int s = __shfl(sv, jj < 64 ? jj : 63);
                unsigned int u = hbu[(size_t)s * 64 + lane];
                if (jj < cnt) {                        // wave-uniform predicate
                    accx += __uint_as_float(u << 16);
                    accy += __uint_as_float(u & 0xffff0000u);
                }
            }
        }
    }
    float din = dinv[wv];
    unsigned int w = (unsigned int)f2bf(accx * din) | ((unsigned int)f2bf(accy * din) << 16);
    ((unsigned int*)outb)[(size_t)wv * 64 + lane] = w;
}

// ================= MFMA GEMM layer 2: [Nx64]bf16 @ [64x128] + b2 -> hb bf16 ======

__global__ __launch_bounds__(256) void k_gemm_l2_mfma(
    const unsigned short* __restrict__ Ab,   // [N][64] bf16
    const unsigned short* __restrict__ Wb,   // packed [8][128][8] bf16
    const float* __restrict__ b,
    const float* __restrict__ dinv,
    unsigned short* __restrict__ hb) {
    __shared__ float sC[64][128];
    int tid = threadIdx.x;
    int wave = tid >> 6, lane = tid & 63;
    int quad = lane >> 4, l16 = lane & 15;
    int n0 = blockIdx.x * 64;
    int arow = n0 + wave * 16 + l16;
    if (arow >= N_NODES) arow = N_NODES - 1;

    floatx4 acc[8];
#pragma unroll
    for (int t = 0; t < 8; ++t) acc[t] = (floatx4){0.f, 0.f, 0.f, 0.f};

#pragma unroll
    for (int ks = 0; ks < 2; ++ks) {
        short8 a = *(const short8*)(Ab + (size_t)arow * 64 + ks * 32 + quad * 8);
#pragma unroll
        for (int t = 0; t < 8; ++t) {
            short8 bf = *(const short8*)(Wb + (((ks * 4 + quad) * 128) + t * 16 + l16) * 8);
            acc[t] = __builtin_amdgcn_mfma_f32_16x16x32_bf16(a, bf, acc[t], 0, 0, 0);
        }
    }
#pragma unroll
    for (int t = 0; t < 8; ++t)
#pragma unroll
        for (int r = 0; r < 4; ++r)
            sC[wave * 16 + quad * 4 + r][t * 16 + l16] = acc[t][r];
    __syncthreads();
    int tn = tid >> 5, tj = tid & 31;
    float4 bv = *(const float4*)(b + tj * 4);
#pragma unroll
    for (int m = 0; m < 8; ++m) {
        int n = n0 + tn * 8 + m;
        if (n < N_NODES) {
            float di = dinv[n];
            unsigned short h0 = f2bf(fmaxf(sC[tn * 8 + m][tj * 4 + 0] + bv.x, 0.f) * di);
            unsigned short h1 = f2bf(fmaxf(sC[tn * 8 + m][tj * 4 + 1] + bv.y, 0.f) * di);
            unsigned short h2 = f2bf(fmaxf(sC[tn * 8 + m][tj * 4 + 2] + bv.z, 0.f) * di);
            unsigned short h3 = f2bf(fmaxf(sC[tn * 8 + m][tj * 4 + 3] + bv.w, 0.f) * di);
            uint2 w2;
            w2.x = (unsigned int)h0 | ((unsigned int)h1 << 16);
            w2.y = (unsigned int)h2 | ((unsigned int)h3 << 16);
            *(uint2*)(hb + (size_t)n * 128 + tj * 4) = w2;
        }
    }
}

// ======== MFMA GEMM layer 3: [Nx128]bf16 @ [128x128] + b3, relu, fused mean-pool ==

__global__ __launch_bounds__(256) void k_gemm_l3_mfma_pool(
    const unsigned short* __restrict__ Ab,   // [N][128] bf16
    const unsigned short* __restrict__ Wb,   // packed [16][128][8] bf16
    const float* __restrict__ b,
    const int* __restrict__ batch,
    float* __restrict__ pooled) {
    __shared__ float sC[64][128];
    __shared__ float red[8][128];
    __shared__ int sb[64];
    int tid = threadIdx.x;
    int wave = tid >> 6, lane = tid & 63;
    int quad = lane >> 4, l16 = lane & 15;
    int n0 = blockIdx.x * 64;
    int arow = n0 + wave * 16 + l16;
    if (arow >= N_NODES) arow = N_NODES - 1;

    floatx4 acc[8];
#pragma unroll
    for (int t = 0; t < 8; ++t) acc[t] = (floatx4){0.f, 0.f, 0.f, 0.f};

#pragma unroll
    for (int ks = 0; ks < 4; ++ks) {
        short8 a = *(const short8*)(Ab + (size_t)arow * 128 + ks * 32 + quad * 8);
#pragma unroll
        for (int t = 0; t < 8; ++t) {
            short8 bf = *(const short8*)(Wb + (((ks * 4 + quad) * 128) + t * 16 + l16) * 8);
            acc[t] = __builtin_amdgcn_mfma_f32_16x16x32_bf16(a, bf, acc[t], 0, 0, 0);
        }
    }
#pragma unroll
    for (int t = 0; t < 8; ++t) {
        float bc = b[t * 16 + l16];
#pragma unroll
        for (int r = 0; r < 4; ++r)
            sC[wave * 16 + quad * 4 + r][t * 16 + l16] = fmaxf(acc[t][r] + bc, 0.f);
    }
    if (tid < 64) {
        int n = n0 + tid;
        sb[tid] = (n < N_NODES) ? batch[n] : -1;
    }
    __syncthreads();
    int g0 = sb[0];
    int last = (n0 + 63 < N_NODES) ? (n0 + 63) : (N_NODES - 1);
    int g1 = batch[last];
    int tn = tid >> 5, tj = tid & 31;
    for (int g = g0; g <= g1; ++g) {
        float p0 = 0.f, p1 = 0.f, p2 = 0.f, p3 = 0.f;
#pragma unroll
        for (int m = 0; m < 8; ++m) {
            if (sb[tn * 8 + m] == g) {
                p0 += sC[tn * 8 + m][tj * 4 + 0];
                p1 += sC[tn * 8 + m][tj * 4 + 1];
                p2 += sC[tn * 8 + m][tj * 4 + 2];
                p3 += sC[tn * 8 + m][tj * 4 + 3];
            }
        }
        red[tn][tj * 4 + 0] = p0;
        red[tn][tj * 4 + 1] = p1;
        red[tn][tj * 4 + 2] = p2;
        red[tn][tj * 4 + 3] = p3;
        __syncthreads();
        if (tid < 128) {
            float s = 0.f;
#pragma unroll
            for (int r = 0; r < 8; ++r) s += red[r][tid];
            atomicAdd(&pooled[g * 128 + tid], s);
        }
        __syncthreads();
    }
}

// ================= final FC head =================

__device__ __forceinline__ int lower_bound_batch(const int* __restrict__ batch, int val) {
    int lo = 0, hi = N_NODES;
    while (lo < hi) {
        int mid = (lo + hi) >> 1;
        if (batch[mid] < val) lo = mid + 1; else hi = mid;
    }
    return lo;
}

__global__ void k_fc(const float* __restrict__ pooled, const int* __restrict__ batch,
                     const float* __restrict__ Wf1, const float* __restrict__ bf1,
                     const float* __restrict__ Wf2, const float* __restrict__ bf2,
                     float* __restrict__ out) {
    __shared__ float sp[128];
    __shared__ float sh1[64];
    int g = blockIdx.x;
    int t = threadIdx.x;             // 128
    int lo = lower_bound_batch(batch, g);
    int hi = lower_bound_batch(batch, g + 1);
    float inv = 1.0f / fmaxf((float)(hi - lo), 1.0f);
    sp[t] = pooled[g * 128 + t] * inv;
    __syncthreads();
    if (t < 64) {
        float acc = bf1[t];
#pragma unroll 8
        for (int k = 0; k < 128; ++k) acc += sp[k] * Wf1[k * 64 + t];
        sh1[t] = fmaxf(acc, 0.0f);
    }
    __syncthreads();
    if (t < 10) {
        float acc = bf2[t];
#pragma unroll 8
        for (int k = 0; k < 64; ++k) acc += sh1[k] * Wf2[k * 10 + t];
        out[g * 10 + t] = acc;
    }
}

extern "C" void kernel_launch(void* const* d_in, const int* in_sizes, int n_in,
                              void* d_out, int out_size, void* d_ws, size_t ws_size,
                              hipStream_t stream) {
    const float* x     = (const float*)d_in[0];
    const int*   ei    = (const int*)d_in[1];
    const int*   batch = (const int*)d_in[2];
    const float* W1  = (const float*)d_in[3];
    const float* b1  = (const float*)d_in[4];
    const float* W2  = (const float*)d_in[5];
    const float* b2  = (const float*)d_in[6];
    const float* W3  = (const float*)d_in[7];
    const float* b3  = (const float*)d_in[8];
    const float* Wf1 = (const float*)d_in[9];
    const float* bf1 = (const float*)d_in[10];
    const float* Wf2 = (const float*)d_in[11];
    const float* bf2 = (const float*)d_in[12];
    float* out = (float*)d_out;

    const int* src = ei;              // edge_index[0]
    const int* dst = ei + N_EDGES;    // edge_index[1]

    // workspace layout
    float* dinv   = (float*)d_ws;                      // N
    int*   counts = (int*)(dinv + N_NODES);            // N
    int*   row_ptr= counts + N_NODES;                  // N+1
    int*   blksum = row_ptr + N_NODES + 1;             // 256
    int*   cursor = blksum + 256;                      // N
    int*   csr_src= cursor + N_NODES;                  // N_EDGES
    float* xs     = (float*)(csr_src + N_EDGES);       // N*3
    float* a3     = xs + (size_t)N_NODES * 3;          // N*3 (agg3 out)
    unsigned short* Wb2 = (unsigned short*)(a3 + (size_t)N_NODES * 3);  // 8192
    unsigned short* Wb3 = Wb2 + 64 * 128;                               // 16384
    size_t ofs = (size_t)(Wb3 + 128 * 128) - (size_t)d_ws;
    ofs = (ofs + 15) & ~(size_t)15;
    unsigned short* bufA = (unsigned short*)((char*)d_ws + ofs);        // N*128 bf16 (agg out)
    unsigned short* hb   = bufA + (size_t)N_NODES * 128;                // N*128 bf16 (gemm out)
    float* pooled = (float*)(hb + (size_t)N_NODES * 128);               // G*128

    const int TB = 256;
    const int GEMM_BLKS = (N_NODES + 63) / 64;
    const int PREP_N = N_NODES + N_GRAPHS * 128 + 64 * 128 + 128 * 128;

    // ---- prep (zero counts+pooled, cast weights) + CSR build ----
    k_prep<<<(PREP_N + TB - 1) / TB, TB, 0, stream>>>(counts, pooled, W2, W3, Wb2, Wb3);
    k_hist<<<(N_EDGES + TB - 1) / TB, TB, 0, stream>>>(dst, counts);
    k_scan1<<<SCAN_NBLK, SCAN_B, 0, stream>>>(counts, row_ptr, blksum);
    k_scan2<<<1, SCAN_B, 0, stream>>>(blksum);
    k_scan3<<<(N_NODES + TB - 1) / TB, TB, 0, stream>>>(row_ptr, blksum, cursor, counts, dinv, x, xs);
    k_fill<<<(N_EDGES + TB - 1) / TB, TB, 0, stream>>>(src, dst, cursor, csr_src);

    // ---- layer 1: agg3(xs) @ W1 + b1 -> hb = bf16(dinv*relu) ----
    k_agg3<<<(N_NODES + TB - 1) / TB, TB, 0, stream>>>(xs, row_ptr, csr_src, dinv, a3);
    k_node_gemm<3, 64, 4><<<(N_NODES + 3) / 4, 64, 0, stream>>>(a3, W1, b1, dinv, hb);

    // ---- layer 2: agg64(hb) -> bufA bf16; MFMA @ W2 + b2 -> hb bf16 ----
    k_agg64<<<(N_NODES * 64 + TB - 1) / TB, TB, 0, stream>>>(hb, row_ptr, csr_src, dinv, bufA);
    k_gemm_l2_mfma<<<GEMM_BLKS, 256, 0, stream>>>(bufA, Wb2, b2, dinv, hb);

    // ---- layer 3: agg128(hb) -> bufA bf16; MFMA @ W3 + b3, relu, fused pool ----
    k_agg128<<<(N_NODES * 64 + TB - 1) / TB, TB, 0, stream>>>(hb, row_ptr, csr_src, dinv, bufA);
    k_gemm_l3_mfma_pool<<<GEMM_BLKS, 256, 0, stream>>>(bufA, Wb3, b3, batch, pooled);

    // ---- FC head ----
    k_fc<<<N_GRAPHS, 128, 0, stream>>>(pooled, batch, Wf1, bf1, Wf2, bf2, out);
}

// Round 11
// 297.227 us; speedup vs baseline: 1.1684x; 1.0373x over previous
//
#include <hip/hip_runtime.h>

#define N_NODES 50000
#define N_EDGES 800000
#define N_GRAPHS 64
#define SCAN_B 256
#define SCAN_NBLK ((N_NODES + SCAN_B - 1) / SCAN_B)   // 196

typedef __attribute__((ext_vector_type(8))) short short8;
typedef __attribute__((ext_vector_type(4))) float floatx4;

// fp32 -> bf16 round-to-nearest-even
__device__ __forceinline__ unsigned short f2bf(float f) {
    unsigned int u = __float_as_uint(f);
    u += 0x7FFFu + ((u >> 16) & 1u);
    return (unsigned short)(u >> 16);
}
__device__ __forceinline__ float bf2f(unsigned short h) {
    return __uint_as_float(((unsigned int)h) << 16);
}
__device__ __forceinline__ float blo(unsigned int u) { return __uint_as_float(u << 16); }
__device__ __forceinline__ float bhi(unsigned int u) { return __uint_as_float(u & 0xffff0000u); }

// ========== prep: zero counts + pooled, cast W2/W3 to packed bf16 B-frag layout ====

__global__ void k_prep(int* counts, float* pooled,
                       const float* __restrict__ W2, const float* __restrict__ W3,
                       unsigned short* Wb2, unsigned short* Wb3) {
    int i = blockIdx.x * blockDim.x + threadIdx.x;
    if (i < N_NODES) counts[i] = 0;
    int j = i - N_NODES;
    if (j >= 0 && j < N_GRAPHS * 128) pooled[j] = 0.0f;
    int k = i - N_NODES - N_GRAPHS * 128;
    if (k >= 0 && k < 64 * 128) {
        int kk = k >> 7, n = k & 127;
        Wb2[(((kk >> 3) * 128) + n) * 8 + (kk & 7)] = f2bf(W2[k]);
    }
    int l = i - N_NODES - N_GRAPHS * 128 - 64 * 128;
    if (l >= 0 && l < 128 * 128) {
        int kk = l >> 7, n = l & 127;
        Wb3[(((kk >> 3) * 128) + n) * 8 + (kk & 7)] = f2bf(W3[l]);
    }
}

// ================= CSR build (real edges only; self-loop analytic) ====

__global__ void k_hist(const int* __restrict__ dst, int* counts) {
    int i = blockIdx.x * blockDim.x + threadIdx.x;
    if (i < N_EDGES) atomicAdd(&counts[dst[i]], 1);
}

__global__ void k_scan1(const int* __restrict__ counts, int* row_ptr, int* blksum) {
    __shared__ int s[SCAN_B];
    int i = blockIdx.x * SCAN_B + threadIdx.x;
    int c = (i < N_NODES) ? counts[i] : 0;
    s[threadIdx.x] = c;
    __syncthreads();
    for (int off = 1; off < SCAN_B; off <<= 1) {
        int v = (threadIdx.x >= off) ? s[threadIdx.x - off] : 0;
        __syncthreads();
        s[threadIdx.x] += v;
        __syncthreads();
    }
    if (i < N_NODES) row_ptr[i] = s[threadIdx.x] - c;   // exclusive
    if (threadIdx.x == SCAN_B - 1) blksum[blockIdx.x] = s[SCAN_B - 1];
}

__global__ void k_scan2(int* blksum) {
    __shared__ int s[SCAN_B];
    int t = threadIdx.x;
    int c = (t < SCAN_NBLK) ? blksum[t] : 0;
    s[t] = c;
    __syncthreads();
    for (int off = 1; off < SCAN_B; off <<= 1) {
        int v = (t >= off) ? s[t - off] : 0;
        __syncthreads();
        s[t] += v;
        __syncthreads();
    }
    if (t < SCAN_NBLK) blksum[t] = s[t] - c;            // exclusive
}

__global__ void k_scan3(int* row_ptr, const int* __restrict__ blksum,
                        int* cursor, const int* __restrict__ counts, float* dinv,
                        const float* __restrict__ x, float* __restrict__ xs) {
    int i = blockIdx.x * blockDim.x + threadIdx.x;
    if (i < N_NODES) {
        int v = row_ptr[i] + blksum[i / SCAN_B];
        row_ptr[i] = v;
        cursor[i] = v;
        float di = rsqrtf((float)(counts[i] + 1));
        dinv[i] = di;
        xs[i * 3 + 0] = x[i * 3 + 0] * di;
        xs[i * 3 + 1] = x[i * 3 + 1] * di;
        xs[i * 3 + 2] = x[i * 3 + 2] * di;
    }
    if (i == 0) row_ptr[N_NODES] = N_EDGES;
}

__global__ void k_fill(const int* __restrict__ src, const int* __restrict__ dst,
                       int* cursor, int* csr_src) {
    int e = blockIdx.x * blockDim.x + threadIdx.x;
    if (e >= N_EDGES) return;
    int pos = atomicAdd(&cursor[dst[e]], 1);
    csr_src[pos] = src[e];
}

// ================= layer 1: agg width 3 + small GEMM ==================

__global__ void k_agg3(const float* __restrict__ xs, const int* __restrict__ row_ptr,
                       const int* __restrict__ csr_src, const float* __restrict__ dinv,
                       float* __restrict__ out) {
    int n = blockIdx.x * blockDim.x + threadIdx.x;
    if (n >= N_NODES) return;
    int lo = row_ptr[n], hi = row_ptr[n + 1];
    float a0 = xs[n * 3 + 0], a1 = xs[n * 3 + 1], a2 = xs[n * 3 + 2];
    for (int i = lo; i < hi; ++i) {
        int s = csr_src[i];
        a0 += xs[s * 3 + 0];
        a1 += xs[s * 3 + 1];
        a2 += xs[s * 3 + 2];
    }
    float din = dinv[n];
    out[n * 3 + 0] = a0 * din;
    out[n * 3 + 1] = a1 * din;
    out[n * 3 + 2] = a2 * din;
}

template<int IN_W, int OUT_W, int NPB>
__global__ void k_node_gemm(const float* __restrict__ h, const float* __restrict__ W,
                            const float* __restrict__ b, const float* __restrict__ dinv,
                            unsigned short* __restrict__ hb) {
    __shared__ float rows[NPB][IN_W];
    int n0 = blockIdx.x * NPB;
    int j = threadIdx.x;                         // blockDim.x == OUT_W
    for (int t = j; t < NPB * IN_W; t += OUT_W) {
        int m = t / IN_W, k = t - m * IN_W;
        int n = n0 + m;
        rows[m][k] = (n < N_NODES) ? h[(size_t)n * IN_W + k] : 0.0f;
    }
    __syncthreads();
    float acc[NPB];
    float bj = b[j];
#pragma unroll
    for (int m = 0; m < NPB; ++m) acc[m] = bj;
#pragma unroll
    for (int k = 0; k < IN_W; ++k) {
        float wk = W[k * OUT_W + j];
#pragma unroll
        for (int m = 0; m < NPB; ++m) acc[m] += rows[m][k] * wk;
    }
#pragma unroll
    for (int m = 0; m < NPB; ++m) {
        int n = n0 + m;
        if (n < N_NODES)
            hb[(size_t)n * OUT_W + j] = f2bf(fmaxf(acc[m], 0.0f) * dinv[n]);
    }
}

// ================= aggregation (wave per node, multi-row dwordx4 gathers) =========
// lane = (edge-slot, 16B-chunk). One wave-instruction fetches SLOTS independent
// rows (1 KB). No shfl broadcast: each lane loads csr_src[e] directly.
// Epilogue: shfl_xor reduce across slots, chunk lanes write the row.

// width 64: row = 128 B = 8 chunks x 16 B -> 8 edge slots
__global__ void k_agg64(const unsigned short* __restrict__ hb, const int* __restrict__ row_ptr,
                        const int* __restrict__ csr_src, const float* __restrict__ dinv,
                        unsigned short* __restrict__ outb) {
    int wv = (blockIdx.x * blockDim.x + threadIdx.x) >> 6;
    int lane = threadIdx.x & 63;
    if (wv >= N_NODES) return;
    int q = lane & 7;           // 16B chunk in row
    int slot = lane >> 3;       // 0..7
    int lo = row_ptr[wv], hi = row_ptr[wv + 1];
    const uint4* hbv = (const uint4*)hb;       // row = 8 x uint4
    float acc[8];
#pragma unroll
    for (int i = 0; i < 8; ++i) acc[i] = 0.f;
    if (slot == 0) {                            // self-loop
        uint4 u = hbv[(size_t)wv * 8 + q];
        acc[0] += blo(u.x); acc[1] += bhi(u.x);
        acc[2] += blo(u.y); acc[3] += bhi(u.y);
        acc[4] += blo(u.z); acc[5] += bhi(u.z);
        acc[6] += blo(u.w); acc[7] += bhi(u.w);
    }
    for (int base = lo; base < hi; base += 32) {
#pragma unroll
        for (int k = 0; k < 4; ++k) {
            int e = base + k * 8 + slot;
            int ee = e < hi ? e : hi - 1;
            int s = csr_src[ee];
            uint4 u = hbv[(size_t)s * 8 + q];
            if (e < hi) {
                acc[0] += blo(u.x); acc[1] += bhi(u.x);
                acc[2] += blo(u.y); acc[3] += bhi(u.y);
                acc[4] += blo(u.z); acc[5] += bhi(u.z);
                acc[6] += blo(u.w); acc[7] += bhi(u.w);
            }
        }
    }
#pragma unroll
    for (int i = 0; i < 8; ++i) {
        acc[i] += __shfl_xor(acc[i], 8);
        acc[i] += __shfl_xor(acc[i], 16);
        acc[i] += __shfl_xor(acc[i], 32);
    }
    if (slot == 0) {
        float din = dinv[wv];
        uint4 w;
        w.x = (unsigned int)f2bf(acc[0] * din) | ((unsigned int)f2bf(acc[1] * din) << 16);
        w.y = (unsigned int)f2bf(acc[2] * din) | ((unsigned int)f2bf(acc[3] * din) << 16);
        w.z = (unsigned int)f2bf(acc[4] * din) | ((unsigned int)f2bf(acc[5] * din) << 16);
        w.w = (unsigned int)f2bf(acc[6] * din) | ((unsigned int)f2bf(acc[7] * din) << 16);
        ((uint4*)outb)[(size_t)wv * 8 + q] = w;
    }
}

// width 128: row = 256 B = 16 chunks x 16 B -> 4 edge slots
__global__ void k_agg128(const unsigned short* __restrict__ hb, const int* __restrict__ row_ptr,
                         const int* __restrict__ csr_src, const float* __restrict__ dinv,
                         unsigned short* __restrict__ outb) {
    int wv = (blockIdx.x * blockDim.x + threadIdx.x) >> 6;
    int lane = threadIdx.x & 63;
    if (wv >= N_NODES) return;
    int q = lane & 15;          // 16B chunk in row
    int slot = lane >> 4;       // 0..3
    int lo = row_ptr[wv], hi = row_ptr[wv + 1];
    const uint4* hbv = (const uint4*)hb;       // row = 16 x uint4
    float acc[8];
#pragma unroll
    for (int i = 0; i < 8; ++i) acc[i] = 0.f;
    if (slot == 0) {                            // self-loop
        uint4 u = hbv[(size_t)wv * 16 + q];
        acc[0] += blo(u.x); acc[1] += bhi(u.x);
        acc[2] += blo(u.y); acc[3] += bhi(u.y);
        acc[4] += blo(u.z); acc[5] += bhi(u.z);
        acc[6] += blo(u.w); acc[7] += bhi(u.w);
    }
    for (int base = lo; base < hi; base += 16) {
#pragma unroll
        for (int k = 0; k < 4; ++k) {
            int e = base + k * 4 + slot;
            int ee = e < hi ? e : hi - 1;
            int s = csr_src[ee];
            uint4 u = hbv[(size_t)s * 16 + q];
            if (e < hi) {
                acc[0] += blo(u.x); acc[1] += bhi(u.x);
                acc[2] += blo(u.y); acc[3] += bhi(u.y);
                acc[4] += blo(u.z); acc[5] += bhi(u.z);
                acc[6] += blo(u.w); acc[7] += bhi(u.w);
            }
        }
    }
#pragma unroll
    for (int i = 0; i < 8; ++i) {
        acc[i] += __shfl_xor(acc[i], 16);
        acc[i] += __shfl_xor(acc[i], 32);
    }
    if (slot == 0) {
        float din = dinv[wv];
        uint4 w;
        w.x = (unsigned int)f2bf(acc[0] * din) | ((unsigned int)f2bf(acc[1] * din) << 16);
        w.y = (unsigned int)f2bf(acc[2] * din) | ((unsigned int)f2bf(acc[3] * din) << 16);
        w.z = (unsigned int)f2bf(acc[4] * din) | ((unsigned int)f2bf(acc[5] * din) << 16);
        w.w = (unsigned int)f2bf(acc[6] * din) | ((unsigned int)f2bf(acc[7] * din) << 16);
        ((uint4*)outb)[(size_t)wv * 16 + q] = w;
    }
}

// ================= MFMA GEMM layer 2: [Nx64]bf16 @ [64x128] + b2 -> hb bf16 ======

__global__ __launch_bounds__(256) void k_gemm_l2_mfma(
    const unsigned short* __restrict__ Ab,   // [N][64] bf16
    const unsigned short* __restrict__ Wb,   // packed [8][128][8] bf16
    const float* __restrict__ b,
    const float* __restrict__ dinv,
    unsigned short* __restrict__ hb) {
    __shared__ float sC[64][128];
    int tid = threadIdx.x;
    int wave = tid >> 6, lane = tid & 63;
    int quad = lane >> 4, l16 = lane & 15;
    int n0 = blockIdx.x * 64;
    int arow = n0 + wave * 16 + l16;
    if (arow >= N_NODES) arow = N_NODES - 1;

    floatx4 acc[8];
#pragma unroll
    for (int t = 0; t < 8; ++t) acc[t] = (floatx4){0.f, 0.f, 0.f, 0.f};

#pragma unroll
    for (int ks = 0; ks < 2; ++ks) {
        short8 a = *(const short8*)(Ab + (size_t)arow * 64 + ks * 32 + quad * 8);
#pragma unroll
        for (int t = 0; t < 8; ++t) {
            short8 bf = *(const short8*)(Wb + (((ks * 4 + quad) * 128) + t * 16 + l16) * 8);
            acc[t] = __builtin_amdgcn_mfma_f32_16x16x32_bf16(a, bf, acc[t], 0, 0, 0);
        }
    }
#pragma unroll
    for (int t = 0; t < 8; ++t)
#pragma unroll
        for (int r = 0; r < 4; ++r)
            sC[wave * 16 + quad * 4 + r][t * 16 + l16] = acc[t][r];
    __syncthreads();
    int tn = tid >> 5, tj = tid & 31;
    float4 bv = *(const float4*)(b + tj * 4);
#pragma unroll
    for (int m = 0; m < 8; ++m) {
        int n = n0 + tn * 8 + m;
        if (n < N_NODES) {
            float di = dinv[n];
            unsigned short h0 = f2bf(fmaxf(sC[tn * 8 + m][tj * 4 + 0] + bv.x, 0.f) * di);
            unsigned short h1 = f2bf(fmaxf(sC[tn * 8 + m][tj * 4 + 1] + bv.y, 0.f) * di);
            unsigned short h2 = f2bf(fmaxf(sC[tn * 8 + m][tj * 4 + 2] + bv.z, 0.f) * di);
            unsigned short h3 = f2bf(fmaxf(sC[tn * 8 + m][tj * 4 + 3] + bv.w, 0.f) * di);
            uint2 w2;
            w2.x = (unsigned int)h0 | ((unsigned int)h1 << 16);
            w2.y = (unsigned int)h2 | ((unsigned int)h3 << 16);
            *(uint2*)(hb + (size_t)n * 128 + tj * 4) = w2;
        }
    }
}

// ======== MFMA GEMM layer 3: [Nx128]bf16 @ [128x128] + b3, relu, fused mean-pool ==

__global__ __launch_bounds__(256) void k_gemm_l3_mfma_pool(
    const unsigned short* __restrict__ Ab,   // [N][128] bf16
    const unsigned short* __restrict__ Wb,   // packed [16][128][8] bf16
    const float* __restrict__ b,
    const int* __restrict__ batch,
    float* __restrict__ pooled) {
    __shared__ float sC[64][128];
    __shared__ float red[8][128];
    __shared__ int sb[64];
    int tid = threadIdx.x;
    int wave = tid >> 6, lane = tid & 63;
    int quad = lane >> 4, l16 = lane & 15;
    int n0 = blockIdx.x * 64;
    int arow = n0 + wave * 16 + l16;
    if (arow >= N_NODES) arow = N_NODES - 1;

    floatx4 acc[8];
#pragma unroll
    for (int t = 0; t < 8; ++t) acc[t] = (floatx4){0.f, 0.f, 0.f, 0.f};

#pragma unroll
    for (int ks = 0; ks < 4; ++ks) {
        short8 a = *(const short8*)(Ab + (size_t)arow * 128 + ks * 32 + quad * 8);
#pragma unroll
        for (int t = 0; t < 8; ++t) {
            short8 bf = *(const short8*)(Wb + (((ks * 4 + quad) * 128) + t * 16 + l16) * 8);
            acc[t] = __builtin_amdgcn_mfma_f32_16x16x32_bf16(a, bf, acc[t], 0, 0, 0);
        }
    }
#pragma unroll
    for (int t = 0; t < 8; ++t) {
        float bc = b[t * 16 + l16];
#pragma unroll
        for (int r = 0; r < 4; ++r)
            sC[wave * 16 + quad * 4 + r][t * 16 + l16] = fmaxf(acc[t][r] + bc, 0.f);
    }
    if (tid < 64) {
        int n = n0 + tid;
        sb[tid] = (n < N_NODES) ? batch[n] : -1;
    }
    __syncthreads();
    int g0 = sb[0];
    int last = (n0 + 63 < N_NODES) ? (n0 + 63) : (N_NODES - 1);
    int g1 = batch[last];
    int tn = tid >> 5, tj = tid & 31;
    for (int g = g0; g <= g1; ++g) {
        float p0 = 0.f, p1 = 0.f, p2 = 0.f, p3 = 0.f;
#pragma unroll
        for (int m = 0; m < 8; ++m) {
            if (sb[tn * 8 + m] == g) {
                p0 += sC[tn * 8 + m][tj * 4 + 0];
                p1 += sC[tn * 8 + m][tj * 4 + 1];
                p2 += sC[tn * 8 + m][tj * 4 + 2];
                p3 += sC[tn * 8 + m][tj * 4 + 3];
            }
        }
        red[tn][tj * 4 + 0] = p0;
        red[tn][tj * 4 + 1] = p1;
        red[tn][tj * 4 + 2] = p2;
        red[tn][tj * 4 + 3] = p3;
        __syncthreads();
        if (tid < 128) {
            float s = 0.f;
#pragma unroll
            for (int r = 0; r < 8; ++r) s += red[r][tid];
            atomicAdd(&pooled[g * 128 + tid], s);
        }
        __syncthreads();
    }
}

// ================= final FC head =================

__device__ __forceinline__ int lower_bound_batch(const int* __restrict__ batch, int val) {
    int lo = 0, hi = N_NODES;
    while (lo < hi) {
        int mid = (lo + hi) >> 1;
        if (batch[mid] < val) lo = mid + 1; else hi = mid;
    }
    return lo;
}

__global__ void k_fc(const float* __restrict__ pooled, const int* __restrict__ batch,
                     const float* __restrict__ Wf1, const float* __restrict__ bf1,
                     const float* __restrict__ Wf2, const float* __restrict__ bf2,
                     float* __restrict__ out) {
    __shared__ float sp[128];
    __shared__ float sh1[64];
    int g = blockIdx.x;
    int t = threadIdx.x;             // 128
    int lo = lower_bound_batch(batch, g);
    int hi = lower_bound_batch(batch, g + 1);
    float inv = 1.0f / fmaxf((float)(hi - lo), 1.0f);
    sp[t] = pooled[g * 128 + t] * inv;
    __syncthreads();
    if (t < 64) {
        float acc = bf1[t];
#pragma unroll 8
        for (int k = 0; k < 128; ++k) acc += sp[k] * Wf1[k * 64 + t];
        sh1[t] = fmaxf(acc, 0.0f);
    }
    __syncthreads();
    if (t < 10) {
        float acc = bf2[t];
#pragma unroll 8
        for (int k = 0; k < 64; ++k) acc += sh1[k] * Wf2[k * 10 + t];
        out[g * 10 + t] = acc;
    }
}

extern "C" void kernel_launch(void* const* d_in, const int* in_sizes, int n_in,
                              void* d_out, int out_size, void* d_ws, size_t ws_size,
                              hipStream_t stream) {
    const float* x     = (const float*)d_in[0];
    const int*   ei    = (const int*)d_in[1];
    const int*   batch = (const int*)d_in[2];
    const float* W1  = (const float*)d_in[3];
    const float* b1  = (const float*)d_in[4];
    const float* W2  = (const float*)d_in[5];
    const float* b2  = (const float*)d_in[6];
    const float* W3  = (const float*)d_in[7];
    const float* b3  = (const float*)d_in[8];
    const float* Wf1 = (const float*)d_in[9];
    const float* bf1 = (const float*)d_in[10];
    const float* Wf2 = (const float*)d_in[11];
    const float* bf2 = (const float*)d_in[12];
    float* out = (float*)d_out;

    const int* src = ei;              // edge_index[0]
    const int* dst = ei + N_EDGES;    // edge_index[1]

    // workspace layout
    float* dinv   = (float*)d_ws;                      // N
    int*   counts = (int*)(dinv + N_NODES);            // N
    int*   row_ptr= counts + N_NODES;                  // N+1
    int*   blksum = row_ptr + N_NODES + 1;             // 256
    int*   cursor = blksum + 256;                      // N
    int*   csr_src= cursor + N_NODES;                  // N_EDGES
    float* xs     = (float*)(csr_src + N_EDGES);       // N*3
    float* a3     = xs + (size_t)N_NODES * 3;          // N*3 (agg3 out)
    unsigned short* Wb2 = (unsigned short*)(a3 + (size_t)N_NODES * 3);  // 8192
    unsigned short* Wb3 = Wb2 + 64 * 128;                               // 16384
    size_t ofs = (size_t)(Wb3 + 128 * 128) - (size_t)d_ws;
    ofs = (ofs + 15) & ~(size_t)15;
    unsigned short* bufA = (unsigned short*)((char*)d_ws + ofs);        // N*128 bf16 (agg out)
    unsigned short* hb   = bufA + (size_t)N_NODES * 128;                // N*128 bf16 (gemm out)
    float* pooled = (float*)(hb + (size_t)N_NODES * 128);               // G*128

    const int TB = 256;
    const int GEMM_BLKS = (N_NODES + 63) / 64;
    const int PREP_N = N_NODES + N_GRAPHS * 128 + 64 * 128 + 128 * 128;

    // ---- prep (zero counts+pooled, cast weights) + CSR build ----
    k_prep<<<(PREP_N + TB - 1) / TB, TB, 0, stream>>>(counts, pooled, W2, W3, Wb2, Wb3);
    k_hist<<<(N_EDGES + TB - 1) / TB, TB, 0, stream>>>(dst, counts);
    k_scan1<<<SCAN_NBLK, SCAN_B, 0, stream>>>(counts, row_ptr, blksum);
    k_scan2<<<1, SCAN_B, 0, stream>>>(blksum);
    k_scan3<<<(N_NODES + TB - 1) / TB, TB, 0, stream>>>(row_ptr, blksum, cursor, counts, dinv, x, xs);
    k_fill<<<(N_EDGES + TB - 1) / TB, TB, 0, stream>>>(src, dst, cursor, csr_src);

    // ---- layer 1: agg3(xs) @ W1 + b1 -> hb = bf16(dinv*relu) ----
    k_agg3<<<(N_NODES + TB - 1) / TB, TB, 0, stream>>>(xs, row_ptr, csr_src, dinv, a3);
    k_node_gemm<3, 64, 4><<<(N_NODES + 3) / 4, 64, 0, stream>>>(a3, W1, b1, dinv, hb);

    // ---- layer 2: agg64(hb) -> bufA bf16; MFMA @ W2 + b2 -> hb bf16 ----
    k_agg64<<<(N_NODES * 64 + TB - 1) / TB, TB, 0, stream>>>(hb, row_ptr, csr_src, dinv, bufA);
    k_gemm_l2_mfma<<<GEMM_BLKS, 256, 0, stream>>>(bufA, Wb2, b2, dinv, hb);

    // ---- layer 3: agg128(hb) -> bufA bf16; MFMA @ W3 + b3, relu, fused pool ----
    k_agg128<<<(N_NODES * 64 + TB - 1) / TB, TB, 0, stream>>>(hb, row_ptr, csr_src, dinv, bufA);
    k_gemm_l3_mfma_pool<<<GEMM_BLKS, 256, 0, stream>>>(bufA, Wb3, b3, batch, pooled);

    // ---- FC head ----
    k_fc<<<N_GRAPHS, 128, 0, stream>>>(pooled, batch, Wf1, bf1, Wf2, bf2, out);
}